// Round 2
// 4651.619 us; speedup vs baseline: 2.1537x; 2.1537x over previous
//
#include <hip/hip_runtime.h>
#include <math.h>

#define LL 4
#define HH 12
#define EE 768
#define TT 1024
#define VV 50257
#define BB 2
#define MM (BB*TT)      // 2048
#define HD 64
#define EPS 1e-5f
#define SCALE 0.03608439182435161f   // 1/sqrt(768)

typedef _Float16 half8 __attribute__((ext_vector_type(8)));
typedef float f32x4 __attribute__((ext_vector_type(4)));

// ---------------- embedding ----------------
__global__ __launch_bounds__(256) void k_embed(const int* __restrict__ idx,
                                               const float* __restrict__ wte,
                                               const float* __restrict__ wpe,
                                               float* __restrict__ x) {
    int row = blockIdx.x;            // 0..M-1
    int t = row % TT;
    int tok = idx[row];
    const float* wt = wte + (size_t)tok * EE;
    const float* wp = wpe + (size_t)t * EE;
    float* xr = x + (size_t)row * EE;
    for (int e = threadIdx.x; e < EE; e += 256)
        xr[e] = wt[e] + wp[e];
}

// ---------------- layernorm ----------------
__device__ __forceinline__ float wred_sum(float v) {
    #pragma unroll
    for (int o = 32; o; o >>= 1) v += __shfl_down(v, o);
    return v;
}
__device__ __forceinline__ float wred_max(float v) {
    #pragma unroll
    for (int o = 32; o; o >>= 1) v = fmaxf(v, __shfl_down(v, o));
    return v;
}

__global__ __launch_bounds__(256) void k_ln(const float* __restrict__ x,
                                            const float* __restrict__ w,
                                            const float* __restrict__ b,
                                            float* __restrict__ out) {
    int row = blockIdx.x;
    int tid = threadIdx.x;
    const float* xr = x + (size_t)row * EE;
    float* orow = out + (size_t)row * EE;
    float vals[3];
    float sum = 0.f, sq = 0.f;
    #pragma unroll
    for (int i = 0; i < 3; ++i) {
        float v = xr[tid + i * 256];
        vals[i] = v; sum += v; sq += v * v;
    }
    __shared__ float r1[4], r2[4];
    int lane = tid & 63, wid = tid >> 6;
    sum = wred_sum(sum); sq = wred_sum(sq);
    if (lane == 0) { r1[wid] = sum; r2[wid] = sq; }
    __syncthreads();
    sum = r1[0] + r1[1] + r1[2] + r1[3];
    sq  = r2[0] + r2[1] + r2[2] + r2[3];
    float mu = sum * (1.f / EE);
    float var = sq * (1.f / EE) - mu * mu;
    float rstd = rsqrtf(var + EPS);
    #pragma unroll
    for (int i = 0; i < 3; ++i) {
        int c = tid + i * 256;
        orow[c] = (vals[i] - mu) * rstd * w[c] + b[c];
    }
}

// ---------------- MFMA GEMM: C = epi(A @ B + bias [+ resid]) ----------------
// A: [M,K] fp32 row-major.  B: [K,N] fp32 row-major, or [N,K] if TRANS_B.
// fp32 -> fp16 conversion happens during LDS staging; fp32 MFMA accumulate.
// Tile 128x128, BK=32, 256 threads = 4 waves in 2x2, each wave 64x64 via
// 4x4 frags of mfma_f32_16x16x32_f16.
// LDS layout: As[row][k] / Bs[col][k], padded to 40 halves (80 B, 16B-aligned,
// 20-bank row stride -> only free 2-way conflicts on ds_read_b128).
// NOTE on operand layout: A-frag and B-frag are both loaded as
// "lane-group lg = lane>>4 covers k = 8*lg + [0..8)". Since one MFMA's K=32
// reduction spans the whole staged k-tile and A/B use the SAME mapping, any
// bijective k-mapping gives the correct sum; only the C/D layout
// (col = lane&15, row = 4*(lane>>4)+reg, HW-verified) must be exact.
// EPI: 0 = none, 1 = tanh-gelu, 2 = add resid (resid is [M,N])
template<bool TRANS_B, int EPI>
__global__ __launch_bounds__(256) void k_gemm(const float* __restrict__ A,
                                              const float* __restrict__ Bm,
                                              const float* __restrict__ bias,
                                              const float* __restrict__ resid,
                                              float* __restrict__ C,
                                              int M, int N, int K) {
    __shared__ _Float16 As[128][40];
    __shared__ _Float16 Bs[128][40];

    // Bijective XCD remap (m204): each XCD gets a contiguous run of linear
    // block ids; with grid.x = row-panels (16), that is a contiguous run of
    // col-panels -> each B col-panel is fetched into ONE XCD's L2 once.
    int nwg = gridDim.x * gridDim.y;
    int o = blockIdx.y * gridDim.x + blockIdx.x;
    int q = nwg >> 3, r = nwg & 7;
    int xcd = o & 7, pos = o >> 3;
    int nid = (xcd < r ? xcd * (q + 1) : r * (q + 1) + (xcd - r) * q) + pos;
    int row0 = (nid % gridDim.x) * 128;
    int col0 = (nid / gridDim.x) * 128;

    int tid = threadIdx.x;
    int lane = tid & 63;
    int wave = tid >> 6;
    int wm = (wave >> 1) * 64, wn = (wave & 1) * 64;
    int lr = lane & 15, lg = lane >> 4;

    const f32x4 zf = {0.f, 0.f, 0.f, 0.f};
    f32x4 acc[4][4];
    #pragma unroll
    for (int i = 0; i < 4; ++i)
        #pragma unroll
        for (int j = 0; j < 4; ++j) acc[i][j] = zf;

    // --- staging index precompute ---
    // A: thread covers row ar, k-halves [ak, ak+16)
    int ar = tid >> 1, ak = (tid & 1) * 16;
    const float* aptr = A + (size_t)(row0 + ar) * K + ak;
    // B: TRANS_B: like A (row = output col). else: thread owns one output col,
    // 16 N-strided loads (lane-coalesced along n).
    int bn, bk;
    bool bvalid;
    const float* bptr;
    if (TRANS_B) {
        bn = tid >> 1; bk = (tid & 1) * 16;
        bvalid = (col0 + bn) < N;
        int bcl = bvalid ? (col0 + bn) : 0;          // clamp: junk cols are
        bptr = Bm + (size_t)bcl * K + bk;            // never stored (col<N guard)
    } else {
        bn = tid & 127; bk = (tid >> 7) * 16;
        bvalid = (col0 + bn) < N;
        int bcl = bvalid ? (col0 + bn) : 0;
        bptr = Bm + (size_t)bk * N + bcl;
    }

    for (int kt = 0; kt < K; kt += 32) {
        // ---- stage A (fp32 -> fp16) ----
        {
            const float* p = aptr + kt;
            half8 v0, v1;
            #pragma unroll
            for (int i = 0; i < 8; ++i) v0[i] = (_Float16)p[i];
            #pragma unroll
            for (int i = 0; i < 8; ++i) v1[i] = (_Float16)p[8 + i];
            *(half8*)&As[ar][ak]     = v0;
            *(half8*)&As[ar][ak + 8] = v1;
        }
        // ---- stage B (fp32 -> fp16), Bs[col][k] ----
        {
            half8 v0, v1;
            if (TRANS_B) {
                const float* p = bptr + kt;
                #pragma unroll
                for (int i = 0; i < 8; ++i) v0[i] = (_Float16)p[i];
                #pragma unroll
                for (int i = 0; i < 8; ++i) v1[i] = (_Float16)p[8 + i];
            } else {
                const float* p = bptr + (size_t)kt * N;
                #pragma unroll
                for (int i = 0; i < 8; ++i) v0[i] = (_Float16)p[(size_t)i * N];
                #pragma unroll
                for (int i = 0; i < 8; ++i) v1[i] = (_Float16)p[(size_t)(8 + i) * N];
            }
            *(half8*)&Bs[bn][bk]     = v0;
            *(half8*)&Bs[bn][bk + 8] = v1;
        }
        __syncthreads();
        // ---- fragments + MFMA ----
        half8 af[4], bf[4];
        #pragma unroll
        for (int i = 0; i < 4; ++i)
            af[i] = *(const half8*)&As[wm + i * 16 + lr][lg * 8];
        #pragma unroll
        for (int j = 0; j < 4; ++j)
            bf[j] = *(const half8*)&Bs[wn + j * 16 + lr][lg * 8];
        #pragma unroll
        for (int i = 0; i < 4; ++i)
            #pragma unroll
            for (int j = 0; j < 4; ++j)
                acc[i][j] = __builtin_amdgcn_mfma_f32_16x16x32_f16(
                    af[i], bf[j], acc[i][j], 0, 0, 0);
        __syncthreads();
    }

    // ---- epilogue: D[4*lg + rr][lr] per frag (HW-verified C/D layout) ----
    #pragma unroll
    for (int j = 0; j < 4; ++j) {
        int col = col0 + wn + j * 16 + lr;
        if (col < N) {
            float bv = bias ? bias[col] : 0.f;
            #pragma unroll
            for (int i = 0; i < 4; ++i) {
                int rbase = row0 + wm + i * 16 + lg * 4;
                #pragma unroll
                for (int rr = 0; rr < 4; ++rr) {
                    float v = acc[i][j][rr] + bv;
                    if (EPI == 1) {
                        float t = tanhf(0.7978845608028654f *
                                        (v + 0.044715f * v * v * v));
                        v = 0.5f * v * (1.f + t);
                    }
                    if (EPI == 2) v += resid[(size_t)(rbase + rr) * N + col];
                    C[(size_t)(rbase + rr) * N + col] = v;
                }
            }
        }
    }
}

// ---------------- attention (flash-style, 1 block per (b,h,q)) ----------------
#define KTILE 128
__global__ __launch_bounds__(256) void k_attn(const float* __restrict__ qkv,
                                              float* __restrict__ y) {
    int q = blockIdx.x, h = blockIdx.y, b = blockIdx.z;
    int tid = threadIdx.x;
    __shared__ float qv[64];
    __shared__ float s[TT];
    __shared__ float tile[KTILE][65];
    __shared__ float red[4];

    const size_t rowstride = 3 * EE;
    const size_t base = (size_t)b * TT * rowstride;
    if (tid < 64) qv[tid] = qkv[base + (size_t)q * rowstride + h * HD + tid];
    __syncthreads();

    int nk = q + 1;
    // ---- scores ----
    for (int t0 = 0; t0 < nk; t0 += KTILE) {
        int cnt = min(KTILE, nk - t0);
        for (int e = tid; e < cnt * 64; e += 256) {
            int r = e >> 6, c = e & 63;
            tile[r][c] = qkv[base + (size_t)(t0 + r) * rowstride + EE + h * HD + c];
        }
        __syncthreads();
        for (int k = tid; k < cnt; k += 256) {
            float acc = 0.f;
            #pragma unroll
            for (int d = 0; d < 64; ++d) acc = fmaf(qv[d], tile[k][d], acc);
            s[t0 + k] = acc * SCALE;
        }
        __syncthreads();
    }
    // ---- softmax over s[0..nk) ----
    float mx = -INFINITY;
    for (int k = tid; k < nk; k += 256) mx = fmaxf(mx, s[k]);
    mx = wred_max(mx);
    int lane = tid & 63, wid = tid >> 6;
    if (lane == 0) red[wid] = mx;
    __syncthreads();
    mx = fmaxf(fmaxf(red[0], red[1]), fmaxf(red[2], red[3]));
    __syncthreads();
    float lsum = 0.f;
    for (int k = tid; k < nk; k += 256) {
        float p = __expf(s[k] - mx);
        s[k] = p;
        lsum += p;
    }
    lsum = wred_sum(lsum);
    if (lane == 0) red[wid] = lsum;
    __syncthreads();
    float linv = 1.f / (red[0] + red[1] + red[2] + red[3]);
    __syncthreads();
    // ---- y = P @ V ----
    int d = tid & 63, g = tid >> 6;   // 4 k-groups of 64 dims
    float acc = 0.f;
    for (int t0 = 0; t0 < nk; t0 += KTILE) {
        int cnt = min(KTILE, nk - t0);
        for (int e = tid; e < cnt * 64; e += 256) {
            int r = e >> 6, c = e & 63;
            tile[r][c] = qkv[base + (size_t)(t0 + r) * rowstride + 2 * EE + h * HD + c];
        }
        __syncthreads();
        for (int k = g; k < cnt; k += 4)
            acc = fmaf(s[t0 + k], tile[k][d], acc);
        __syncthreads();
    }
    float* flat = &tile[0][0];
    flat[g * 64 + d] = acc;
    __syncthreads();
    if (tid < 64) {
        float r = flat[tid] + flat[64 + tid] + flat[128 + tid] + flat[192 + tid];
        y[(size_t)(b * TT + q) * EE + h * HD + tid] = r * linv;
    }
}

// ---------------- launch ----------------
extern "C" void kernel_launch(void* const* d_in, const int* in_sizes, int n_in,
                              void* d_out, int out_size, void* d_ws, size_t ws_size,
                              hipStream_t stream) {
    const int*   idx    = (const int*)  d_in[0];
    const float* wte    = (const float*)d_in[1];
    const float* wpe    = (const float*)d_in[2];
    const float* ln1_w  = (const float*)d_in[3];
    const float* ln1_b  = (const float*)d_in[4];
    const float* attn_w = (const float*)d_in[5];
    const float* attn_b = (const float*)d_in[6];
    const float* atp_w  = (const float*)d_in[7];
    const float* atp_b  = (const float*)d_in[8];
    const float* ln2_w  = (const float*)d_in[9];
    const float* ln2_b  = (const float*)d_in[10];
    const float* fc_w   = (const float*)d_in[11];
    const float* fc_b   = (const float*)d_in[12];
    const float* pr_w   = (const float*)d_in[13];
    const float* pr_b   = (const float*)d_in[14];
    const float* lnf_w  = (const float*)d_in[15];
    const float* lnf_b  = (const float*)d_in[16];
    float* out = (float*)d_out;

    float* ws = (float*)d_ws;
    float* x    = ws;                    // M*E
    float* h    = x    + (size_t)MM * EE;
    float* qkv  = h    + (size_t)MM * EE;          // M*3E
    float* y    = qkv  + (size_t)MM * 3 * EE;      // M*E
    float* mlp  = y    + (size_t)MM * EE;          // M*4E

    k_embed<<<MM, 256, 0, stream>>>(idx, wte, wpe, x);

    for (int i = 0; i < LL; ++i) {
        k_ln<<<MM, 256, 0, stream>>>(x, ln1_w + i * EE, ln1_b + i * EE, h);
        k_gemm<false, 0><<<dim3(16, 18), 256, 0, stream>>>(
            h, attn_w + (size_t)i * EE * 3 * EE, attn_b + i * 3 * EE, nullptr,
            qkv, MM, 3 * EE, EE);
        k_attn<<<dim3(TT, HH, BB), 256, 0, stream>>>(qkv, y);
        k_gemm<false, 2><<<dim3(16, 6), 256, 0, stream>>>(
            y, atp_w + (size_t)i * EE * EE, atp_b + i * EE, x,
            x, MM, EE, EE);
        k_ln<<<MM, 256, 0, stream>>>(x, ln2_w + i * EE, ln2_b + i * EE, h);
        k_gemm<false, 1><<<dim3(16, 24), 256, 0, stream>>>(
            h, fc_w + (size_t)i * EE * 4 * EE, fc_b + i * 4 * EE, nullptr,
            mlp, MM, 4 * EE, EE);
        k_gemm<false, 2><<<dim3(16, 6), 256, 0, stream>>>(
            mlp, pr_w + (size_t)i * 4 * EE * EE, pr_b + i * EE, x,
            x, MM, EE, 4 * EE);
    }

    k_ln<<<MM, 256, 0, stream>>>(x, lnf_w, lnf_b, h);
    k_gemm<true, 0><<<dim3(16, (VV + 127) / 128), 256, 0, stream>>>(
        h, wte, nullptr, nullptr, out, MM, VV, EE);
}

// Round 3
// 2088.504 us; speedup vs baseline: 4.7968x; 2.2272x over previous
//
#include <hip/hip_runtime.h>
#include <math.h>

#define LL 4
#define HH 12
#define EE 768
#define TT 1024
#define VV 50257
#define BB 2
#define MM (BB*TT)      // 2048
#define HD 64
#define EPS 1e-5f
#define SCALE 0.03608439182435161f   // 1/sqrt(768)

typedef _Float16 half8 __attribute__((ext_vector_type(8)));
typedef float f32x4 __attribute__((ext_vector_type(4)));

// ---------------- embedding ----------------
__global__ __launch_bounds__(256) void k_embed(const int* __restrict__ idx,
                                               const float* __restrict__ wte,
                                               const float* __restrict__ wpe,
                                               float* __restrict__ x) {
    int row = blockIdx.x;            // 0..M-1
    int t = row % TT;
    int tok = idx[row];
    const float* wt = wte + (size_t)tok * EE;
    const float* wp = wpe + (size_t)t * EE;
    float* xr = x + (size_t)row * EE;
    for (int e = threadIdx.x; e < EE; e += 256)
        xr[e] = wt[e] + wp[e];
}

// ---------------- layernorm ----------------
__device__ __forceinline__ float wred_sum(float v) {
    #pragma unroll
    for (int o = 32; o; o >>= 1) v += __shfl_down(v, o);
    return v;
}

__global__ __launch_bounds__(256) void k_ln(const float* __restrict__ x,
                                            const float* __restrict__ w,
                                            const float* __restrict__ b,
                                            float* __restrict__ out) {
    int row = blockIdx.x;
    int tid = threadIdx.x;
    const float* xr = x + (size_t)row * EE;
    float* orow = out + (size_t)row * EE;
    float vals[3];
    float sum = 0.f, sq = 0.f;
    #pragma unroll
    for (int i = 0; i < 3; ++i) {
        float v = xr[tid + i * 256];
        vals[i] = v; sum += v; sq += v * v;
    }
    __shared__ float r1[4], r2[4];
    int lane = tid & 63, wid = tid >> 6;
    sum = wred_sum(sum); sq = wred_sum(sq);
    if (lane == 0) { r1[wid] = sum; r2[wid] = sq; }
    __syncthreads();
    sum = r1[0] + r1[1] + r1[2] + r1[3];
    sq  = r2[0] + r2[1] + r2[2] + r2[3];
    float mu = sum * (1.f / EE);
    float var = sq * (1.f / EE) - mu * mu;
    float rstd = rsqrtf(var + EPS);
    #pragma unroll
    for (int i = 0; i < 3; ++i) {
        int c = tid + i * 256;
        orow[c] = (vals[i] - mu) * rstd * w[c] + b[c];
    }
}

// ---------------- MFMA GEMM: C = epi(A @ B + bias [+ resid]) ----------------
// (unchanged from round 2 — verified correct + fast)
template<bool TRANS_B, int EPI>
__global__ __launch_bounds__(256) void k_gemm(const float* __restrict__ A,
                                              const float* __restrict__ Bm,
                                              const float* __restrict__ bias,
                                              const float* __restrict__ resid,
                                              float* __restrict__ C,
                                              int M, int N, int K) {
    __shared__ _Float16 As[128][40];
    __shared__ _Float16 Bs[128][40];

    // Bijective XCD remap (m204)
    int nwg = gridDim.x * gridDim.y;
    int o = blockIdx.y * gridDim.x + blockIdx.x;
    int q = nwg >> 3, r = nwg & 7;
    int xcd = o & 7, pos = o >> 3;
    int nid = (xcd < r ? xcd * (q + 1) : r * (q + 1) + (xcd - r) * q) + pos;
    int row0 = (nid % gridDim.x) * 128;
    int col0 = (nid / gridDim.x) * 128;

    int tid = threadIdx.x;
    int lane = tid & 63;
    int wave = tid >> 6;
    int wm = (wave >> 1) * 64, wn = (wave & 1) * 64;
    int lr = lane & 15, lg = lane >> 4;

    const f32x4 zf = {0.f, 0.f, 0.f, 0.f};
    f32x4 acc[4][4];
    #pragma unroll
    for (int i = 0; i < 4; ++i)
        #pragma unroll
        for (int j = 0; j < 4; ++j) acc[i][j] = zf;

    int ar = tid >> 1, ak = (tid & 1) * 16;
    const float* aptr = A + (size_t)(row0 + ar) * K + ak;
    int bn, bk;
    const float* bptr;
    if (TRANS_B) {
        bn = tid >> 1; bk = (tid & 1) * 16;
        int bcl = ((col0 + bn) < N) ? (col0 + bn) : 0;
        bptr = Bm + (size_t)bcl * K + bk;
    } else {
        bn = tid & 127; bk = (tid >> 7) * 16;
        int bcl = ((col0 + bn) < N) ? (col0 + bn) : 0;
        bptr = Bm + (size_t)bk * N + bcl;
    }

    for (int kt = 0; kt < K; kt += 32) {
        {
            const float* p = aptr + kt;
            half8 v0, v1;
            #pragma unroll
            for (int i = 0; i < 8; ++i) v0[i] = (_Float16)p[i];
            #pragma unroll
            for (int i = 0; i < 8; ++i) v1[i] = (_Float16)p[8 + i];
            *(half8*)&As[ar][ak]     = v0;
            *(half8*)&As[ar][ak + 8] = v1;
        }
        {
            half8 v0, v1;
            if (TRANS_B) {
                const float* p = bptr + kt;
                #pragma unroll
                for (int i = 0; i < 8; ++i) v0[i] = (_Float16)p[i];
                #pragma unroll
                for (int i = 0; i < 8; ++i) v1[i] = (_Float16)p[8 + i];
            } else {
                const float* p = bptr + (size_t)kt * N;
                #pragma unroll
                for (int i = 0; i < 8; ++i) v0[i] = (_Float16)p[(size_t)i * N];
                #pragma unroll
                for (int i = 0; i < 8; ++i) v1[i] = (_Float16)p[(size_t)(8 + i) * N];
            }
            *(half8*)&Bs[bn][bk]     = v0;
            *(half8*)&Bs[bn][bk + 8] = v1;
        }
        __syncthreads();
        half8 af[4], bf[4];
        #pragma unroll
        for (int i = 0; i < 4; ++i)
            af[i] = *(const half8*)&As[wm + i * 16 + lr][lg * 8];
        #pragma unroll
        for (int j = 0; j < 4; ++j)
            bf[j] = *(const half8*)&Bs[wn + j * 16 + lr][lg * 8];
        #pragma unroll
        for (int i = 0; i < 4; ++i)
            #pragma unroll
            for (int j = 0; j < 4; ++j)
                acc[i][j] = __builtin_amdgcn_mfma_f32_16x16x32_f16(
                    af[i], bf[j], acc[i][j], 0, 0, 0);
        __syncthreads();
    }

    #pragma unroll
    for (int j = 0; j < 4; ++j) {
        int col = col0 + wn + j * 16 + lr;
        if (col < N) {
            float bv = bias ? bias[col] : 0.f;
            #pragma unroll
            for (int i = 0; i < 4; ++i) {
                int rbase = row0 + wm + i * 16 + lg * 4;
                #pragma unroll
                for (int rr = 0; rr < 4; ++rr) {
                    float v = acc[i][j][rr] + bv;
                    if (EPI == 1) {
                        float t = tanhf(0.7978845608028654f *
                                        (v + 0.044715f * v * v * v));
                        v = 0.5f * v * (1.f + t);
                    }
                    if (EPI == 2) v += resid[(size_t)(rbase + rr) * N + col];
                    C[(size_t)(rbase + rr) * N + col] = v;
                }
            }
        }
    }
}

// ---------------- MFMA flash attention ----------------
// Block = 64 q-rows of one (b,h). 4 waves, each owns 16 q-rows.
// K/V tiles of 64 rows staged fp32->fp16 in LDS once per block-tile.
// Swapped QK^T: S^T = mfma(A=K, B=Q)  -> lane holds q = lane&15, k = 16i+4lg+rr.
//   Row softmax = in-lane reduce over 16 vals + shfl_xor(16) + shfl_xor(32).
// Swapped PV:   O^T += mfma(A=Vfrag, B=Pfrag) -> O^T keeps q = lane&15, so the
//   online rescale (exp(m_old-m_new)) and final 1/l are lane-local (no shuffles).
// k-slot mapping for PV operands: sigma(lg, a, rr) = 16a + 4lg + rr applied
// identically to P (from S^T C/D layout) and V (LDS reads) — same-sigma-on-
// both-operands correctness is what the passing GEMM validated.
#define QBLK 64
#define KT 64
#define LDP 72   // padded row (halves): 144 B, 16B-aligned
__global__ __launch_bounds__(256) void k_attn(const float* __restrict__ qkv,
                                              float* __restrict__ y) {
    int qb = gridDim.x - 1 - blockIdx.x;   // heavy blocks (high q0) first
    int h = blockIdx.y, b = blockIdx.z;
    int q0 = qb * QBLK;
    int tid = threadIdx.x;
    int lane = tid & 63, w = tid >> 6;
    int lr = lane & 15, lg = lane >> 4;

    __shared__ _Float16 Qs[QBLK][LDP];
    __shared__ _Float16 Ks[KT][LDP];
    __shared__ _Float16 Vs[KT][LDP];

    const size_t rowstride = 3 * EE;
    const float* base = qkv + (size_t)b * TT * rowstride + h * HD;

    // ---- stage Q once (64 rows x 64 d) ----
    {
        int r = tid >> 2, c0 = (tid & 3) * 16;
        const float* src = base + (size_t)(q0 + r) * rowstride + c0;
        half8 h0, h1;
        #pragma unroll
        for (int i = 0; i < 8; ++i) h0[i] = (_Float16)src[i];
        #pragma unroll
        for (int i = 0; i < 8; ++i) h1[i] = (_Float16)src[8 + i];
        *(half8*)&Qs[r][c0]     = h0;
        *(half8*)&Qs[r][c0 + 8] = h1;
    }
    __syncthreads();
    // Q-frags (B-operand): q = q0 + 16w + lr, d-chains c: d = 32c + 8lg + e
    half8 qf[2];
    qf[0] = *(const half8*)&Qs[16 * w + lr][lg * 8];
    qf[1] = *(const half8*)&Qs[16 * w + lr][32 + lg * 8];

    int q0w = q0 + 16 * w;
    int qg  = q0w + lr;          // this lane's q-row (softmax state owner)

    float m_run = -INFINITY, l_run = 0.f;
    const f32x4 zf = {0.f, 0.f, 0.f, 0.f};
    f32x4 od[4];                 // O^T frags: d-frag j, row d=16j+4lg+rr, col q=lr
    #pragma unroll
    for (int j = 0; j < 4; ++j) od[j] = zf;

    int nt = qb + 1;
    for (int t = 0; t < nt; ++t) {
        int k0 = t * KT;
        __syncthreads();         // previous tile's LDS reads done
        // ---- stage K,V (64 rows x 64 d each) ----
        {
            int r = tid >> 2, c0 = (tid & 3) * 16;
            const float* ks = base + (size_t)(k0 + r) * rowstride + EE + c0;
            const float* vs = base + (size_t)(k0 + r) * rowstride + 2 * EE + c0;
            half8 a0, a1, b0, b1;
            #pragma unroll
            for (int i = 0; i < 8; ++i) { a0[i] = (_Float16)ks[i]; a1[i] = (_Float16)ks[8 + i]; }
            #pragma unroll
            for (int i = 0; i < 8; ++i) { b0[i] = (_Float16)vs[i]; b1[i] = (_Float16)vs[8 + i]; }
            *(half8*)&Ks[r][c0]     = a0;
            *(half8*)&Ks[r][c0 + 8] = a1;
            *(half8*)&Vs[r][c0]     = b0;
            *(half8*)&Vs[r][c0 + 8] = b1;
        }
        __syncthreads();
        bool active = (k0 <= q0w + 15);
        if (active) {
            // ---- S^T = K @ Q^T (swapped) ----
            f32x4 sf[4];
            #pragma unroll
            for (int i = 0; i < 4; ++i) sf[i] = zf;
            #pragma unroll
            for (int i = 0; i < 4; ++i) {
                half8 kf0 = *(const half8*)&Ks[16 * i + lr][lg * 8];
                half8 kf1 = *(const half8*)&Ks[16 * i + lr][32 + lg * 8];
                sf[i] = __builtin_amdgcn_mfma_f32_16x16x32_f16(kf0, qf[0], sf[i], 0, 0, 0);
                sf[i] = __builtin_amdgcn_mfma_f32_16x16x32_f16(kf1, qf[1], sf[i], 0, 0, 0);
            }
            // ---- scale + causal mask + tile max ----
            float sv[4][4];
            float mt = -INFINITY;
            #pragma unroll
            for (int i = 0; i < 4; ++i)
                #pragma unroll
                for (int rr = 0; rr < 4; ++rr) {
                    int kg = k0 + 16 * i + 4 * lg + rr;
                    float s = (kg <= qg) ? sf[i][rr] * SCALE : -INFINITY;
                    sv[i][rr] = s;
                    mt = fmaxf(mt, s);
                }
            mt = fmaxf(mt, __shfl_xor(mt, 16));
            mt = fmaxf(mt, __shfl_xor(mt, 32));
            float m_new = fmaxf(m_run, mt);
            float fac = __expf(m_run - m_new);
            // ---- P = exp(S - m), pack fp16 B-operand frags ----
            half8 pf[2];
            float lt = 0.f;
            #pragma unroll
            for (int a2 = 0; a2 < 2; ++a2)
                #pragma unroll
                for (int a = 0; a < 2; ++a)
                    #pragma unroll
                    for (int rr = 0; rr < 4; ++rr) {
                        float p = __expf(sv[2 * a2 + a][rr] - m_new);
                        lt += p;
                        pf[a2][4 * a + rr] = (_Float16)p;
                    }
            lt += __shfl_xor(lt, 16);
            lt += __shfl_xor(lt, 32);
            l_run = l_run * fac + lt;
            m_run = m_new;
            #pragma unroll
            for (int j = 0; j < 4; ++j)
                #pragma unroll
                for (int rr = 0; rr < 4; ++rr) od[j][rr] *= fac;
            // ---- O^T += V^T @ P  (A = V-frag with sigma, B = P-frag) ----
            #pragma unroll
            for (int a2 = 0; a2 < 2; ++a2)
                #pragma unroll
                for (int j = 0; j < 4; ++j) {
                    half8 vf;
                    #pragma unroll
                    for (int a = 0; a < 2; ++a)
                        #pragma unroll
                        for (int rr = 0; rr < 4; ++rr)
                            vf[4 * a + rr] = Vs[32 * a2 + 16 * a + 4 * lg + rr][16 * j + lr];
                    od[j] = __builtin_amdgcn_mfma_f32_16x16x32_f16(vf, pf[a2], od[j], 0, 0, 0);
                }
        }
    }
    // ---- normalize + write: y[q][h*64 + d], q = q0w+lr, d = 16j+4lg+rr ----
    float linv = 1.f / l_run;
    size_t orow = (size_t)(b * TT + q0w + lr) * EE + h * HD;
    #pragma unroll
    for (int j = 0; j < 4; ++j)
        #pragma unroll
        for (int rr = 0; rr < 4; ++rr)
            y[orow + 16 * j + 4 * lg + rr] = od[j][rr] * linv;
}

// ---------------- launch ----------------
extern "C" void kernel_launch(void* const* d_in, const int* in_sizes, int n_in,
                              void* d_out, int out_size, void* d_ws, size_t ws_size,
                              hipStream_t stream) {
    const int*   idx    = (const int*)  d_in[0];
    const float* wte    = (const float*)d_in[1];
    const float* wpe    = (const float*)d_in[2];
    const float* ln1_w  = (const float*)d_in[3];
    const float* ln1_b  = (const float*)d_in[4];
    const float* attn_w = (const float*)d_in[5];
    const float* attn_b = (const float*)d_in[6];
    const float* atp_w  = (const float*)d_in[7];
    const float* atp_b  = (const float*)d_in[8];
    const float* ln2_w  = (const float*)d_in[9];
    const float* ln2_b  = (const float*)d_in[10];
    const float* fc_w   = (const float*)d_in[11];
    const float* fc_b   = (const float*)d_in[12];
    const float* pr_w   = (const float*)d_in[13];
    const float* pr_b   = (const float*)d_in[14];
    const float* lnf_w  = (const float*)d_in[15];
    const float* lnf_b  = (const float*)d_in[16];
    float* out = (float*)d_out;

    float* ws = (float*)d_ws;
    float* x    = ws;                    // M*E
    float* h    = x    + (size_t)MM * EE;
    float* qkv  = h    + (size_t)MM * EE;          // M*3E
    float* y    = qkv  + (size_t)MM * 3 * EE;      // M*E
    float* mlp  = y    + (size_t)MM * EE;          // M*4E

    k_embed<<<MM, 256, 0, stream>>>(idx, wte, wpe, x);

    for (int i = 0; i < LL; ++i) {
        k_ln<<<MM, 256, 0, stream>>>(x, ln1_w + i * EE, ln1_b + i * EE, h);
        k_gemm<false, 0><<<dim3(16, 18), 256, 0, stream>>>(
            h, attn_w + (size_t)i * EE * 3 * EE, attn_b + i * 3 * EE, nullptr,
            qkv, MM, 3 * EE, EE);
        k_attn<<<dim3(TT / QBLK, HH, BB), 256, 0, stream>>>(qkv, y);
        k_gemm<false, 2><<<dim3(16, 6), 256, 0, stream>>>(
            y, atp_w + (size_t)i * EE * EE, atp_b + i * EE, x,
            x, MM, EE, EE);
        k_ln<<<MM, 256, 0, stream>>>(x, ln2_w + i * EE, ln2_b + i * EE, h);
        k_gemm<false, 1><<<dim3(16, 24), 256, 0, stream>>>(
            h, fc_w + (size_t)i * EE * 4 * EE, fc_b + i * 4 * EE, nullptr,
            mlp, MM, 4 * EE, EE);
        k_gemm<false, 2><<<dim3(16, 6), 256, 0, stream>>>(
            mlp, pr_w + (size_t)i * 4 * EE * EE, pr_b + i * EE, x,
            x, MM, EE, 4 * EE);
    }

    k_ln<<<MM, 256, 0, stream>>>(x, lnf_w, lnf_b, h);
    k_gemm<true, 0><<<dim3(16, (VV + 127) / 128), 256, 0, stream>>>(
        h, wte, nullptr, nullptr, out, MM, VV, EE);
}